// Round 6
// baseline (467.921 us; speedup 1.0000x reference)
//
#include <hip/hip_runtime.h>
#include <hip/hip_bf16.h>

typedef float f32x4 __attribute__((ext_vector_type(4)));
typedef __bf16 bf16x8 __attribute__((ext_vector_type(8)));

__device__ __forceinline__ unsigned short f2bf(float f) {
    union { float f; unsigned int u; } v; v.f = f;
    unsigned int u = v.u;
    unsigned int r = (u + 0x7fffu + ((u >> 16) & 1u)) >> 16;
    return (unsigned short)r;
}
__device__ __forceinline__ float bf2f(unsigned short u) {
    union { unsigned int u; float f; } v; v.u = ((unsigned int)u) << 16;
    return v.f;
}

// 8 fp32 -> 8 bf16 packed as uint4, via v_cvt_pk_bf16_f32 (T12 recipe).
// cvt_pk packs S0 into low 16, S1 into high 16 == little-endian pair order.
__device__ __forceinline__ uint4 cvt8(float4 lo, float4 hi) {
    uint4 r;
    asm("v_cvt_pk_bf16_f32 %0, %1, %2" : "=v"(r.x) : "v"(lo.x), "v"(lo.y));
    asm("v_cvt_pk_bf16_f32 %0, %1, %2" : "=v"(r.y) : "v"(lo.z), "v"(lo.w));
    asm("v_cvt_pk_bf16_f32 %0, %1, %2" : "=v"(r.z) : "v"(hi.x), "v"(hi.y));
    asm("v_cvt_pk_bf16_f32 %0, %1, %2" : "=v"(r.w) : "v"(hi.z), "v"(hi.w));
    return r;
}

// Raw workgroup barrier WITHOUT the vmcnt(0) drain __syncthreads() emits.
// 0xC07F = vmcnt(63) | expcnt(7) | lgkmcnt(0): wait only for LDS ops, leave
// global prefetch loads in flight across the barrier (m139-validated recipe).
__device__ __forceinline__ void block_sync_lgkm() {
    __asm__ __volatile__("" ::: "memory");
    __builtin_amdgcn_s_waitcnt(0xC07F);
    __builtin_amdgcn_s_barrier();
    __asm__ __volatile__("" ::: "memory");
}

// ---------------------------------------------------------------------------
// GEMM 1 (R2-proven reg-staged 128x64/BK=32 structure, 24 KB LDS) with the
// fp32->bf16 conversion FUSED into staging (k_cvt deleted): loads v_inv/in_w
// as fp32, converts via cvt8 at LDS-write time. MFMA path + Vfrag epilogue
// byte-identical to the proven kernel.
// proj[r][e] = sum_d v_inv[r][d]*in_w[e][d] + in_b[e], written as Vfrag.
// ---------------------------------------------------------------------------
__global__ __launch_bounds__(256, 2) void k_gemm_in(const float* __restrict__ A,
                                                    const float* __restrict__ B,
                                                    const float* __restrict__ bias,
                                                    unsigned short* __restrict__ Vfrag) {
    __shared__ __align__(16) unsigned short As[2][128 * 32];
    __shared__ __align__(16) unsigned short Bs[2][64 * 32];
    const int t = threadIdx.x;
    const int wv = t >> 6, lane = t & 63, mr = lane & 15, quad = lane >> 4;
    const int wi = wv >> 1, wj = wv & 1;
    const int m0 = blockIdx.y * 128, n0 = blockIdx.x * 64;

    f32x4 acc[4][2] = {};
    const int ra0 = t >> 2, ra1 = (t >> 2) + 64, rb = t >> 2;
    const int koff = (t & 3) * 8;

    const float* pA0 = A + (size_t)(m0 + ra0) * 1024 + koff;
    const float* pA1 = A + (size_t)(m0 + ra1) * 1024 + koff;
    const float* pB  = B + (size_t)(n0 + rb)  * 1024 + koff;

    float4 a0l = *(const float4*)pA0, a0h = *(const float4*)(pA0 + 4);
    float4 a1l = *(const float4*)pA1, a1h = *(const float4*)(pA1 + 4);
    float4 b0l = *(const float4*)pB,  b0h = *(const float4*)(pB + 4);

    for (int kb = 0; kb < 32; kb++) {
        unsigned short* as = As[kb & 1];
        unsigned short* bs = Bs[kb & 1];
        *(uint4*)&as[ra0 * 32 + koff] = cvt8(a0l, a0h);
        *(uint4*)&as[ra1 * 32 + koff] = cvt8(a1l, a1h);
        *(uint4*)&bs[rb  * 32 + koff] = cvt8(b0l, b0h);
        if (kb < 31) {
            int kk = (kb + 1) * 32;
            a0l = *(const float4*)(pA0 + kk); a0h = *(const float4*)(pA0 + kk + 4);
            a1l = *(const float4*)(pA1 + kk); a1h = *(const float4*)(pA1 + kk + 4);
            b0l = *(const float4*)(pB + kk);  b0h = *(const float4*)(pB + kk + 4);
        }
        block_sync_lgkm();
        bf16x8 af[4], bf[2];
        #pragma unroll
        for (int i = 0; i < 4; i++)
            af[i] = *(const bf16x8*)&as[(wi * 64 + i * 16 + mr) * 32 + quad * 8];
        #pragma unroll
        for (int j = 0; j < 2; j++)
            bf[j] = *(const bf16x8*)&bs[(wj * 32 + j * 16 + mr) * 32 + quad * 8];
        #pragma unroll
        for (int i = 0; i < 4; i++)
        #pragma unroll
        for (int j = 0; j < 2; j++)
            acc[i][j] = __builtin_amdgcn_mfma_f32_16x16x32_bf16(af[i], bf[j], acc[i][j], 0, 0, 0);
    }
    // epilogue: coalesced Vfrag fragment store (512 B per wave-instr)
    #pragma unroll
    for (int i = 0; i < 4; i++)
    #pragma unroll
    for (int j = 0; j < 2; j++) {
        int col = n0 + wj * 32 + j * 16 + mr;         // e
        int row0 = m0 + wi * 64 + i * 16 + quad * 4;  // r
        float be = bias[col];
        int h = col >> 7, d = col & 127;
        int bb = row0 >> 11, k = row0 & 2047;
        size_t idx8 = ((((size_t)(bb * 8 + h) * 64 + (k >> 5)) * 8 + (d >> 4)) * 64
                       + ((k >> 3) & 3) * 16 + (d & 15));
        int j0 = (quad & 1) * 4;
        ushort4 pk;
        pk.x = f2bf(acc[i][j][0] + be);
        pk.y = f2bf(acc[i][j][1] + be);
        pk.z = f2bf(acc[i][j][2] + be);
        pk.w = f2bf(acc[i][j][3] + be);
        *(ushort4*)(Vfrag + idx8 * 8 + j0) = pk;
    }
}

// ---------------------------------------------------------------------------
// GEMM 2 (R2-proven structure, conversion fused): out_w staged from fp32 via
// cvt8; AOS (bf16 from attn) staged as-is. out[r][e] = sum_d AOS[r][d]*
// out_w[e][d] + out_b[e] (fp32 out). Lane holds 4 consecutive e at fixed r
// => aligned float4 stores.
// ---------------------------------------------------------------------------
__global__ __launch_bounds__(256, 2) void k_gemm_out(const float* __restrict__ W,
                                                     const unsigned short* __restrict__ AOS,
                                                     const float* __restrict__ bias,
                                                     float* __restrict__ out) {
    __shared__ __align__(16) unsigned short As[2][128 * 32];
    __shared__ __align__(16) unsigned short Bs[2][64 * 32];
    const int t = threadIdx.x;
    const int wv = t >> 6, lane = t & 63, mr = lane & 15, quad = lane >> 4;
    const int wi = wv >> 1, wj = wv & 1;
    const int e0 = blockIdx.y * 128, r0 = blockIdx.x * 64;

    f32x4 acc[4][2] = {};
    const int ra0 = t >> 2, ra1 = (t >> 2) + 64, rb = t >> 2;
    const int koff = (t & 3) * 8;

    const float* pW0 = W + (size_t)(e0 + ra0) * 1024 + koff;
    const float* pW1 = W + (size_t)(e0 + ra1) * 1024 + koff;

    float4 w0l = *(const float4*)pW0, w0h = *(const float4*)(pW0 + 4);
    float4 w1l = *(const float4*)pW1, w1h = *(const float4*)(pW1 + 4);
    uint4 pb  = *(const uint4*)(AOS + (size_t)(r0 + rb) * 1024 + koff);

    for (int kb = 0; kb < 32; kb++) {
        unsigned short* as = As[kb & 1];
        unsigned short* bs = Bs[kb & 1];
        *(uint4*)&as[ra0 * 32 + koff] = cvt8(w0l, w0h);
        *(uint4*)&as[ra1 * 32 + koff] = cvt8(w1l, w1h);
        *(uint4*)&bs[rb  * 32 + koff] = pb;
        if (kb < 31) {
            int kk = (kb + 1) * 32;
            w0l = *(const float4*)(pW0 + kk); w0h = *(const float4*)(pW0 + kk + 4);
            w1l = *(const float4*)(pW1 + kk); w1h = *(const float4*)(pW1 + kk + 4);
            pb  = *(const uint4*)(AOS + (size_t)(r0 + rb) * 1024 + kk + koff);
        }
        block_sync_lgkm();
        bf16x8 af[4], bf[2];
        #pragma unroll
        for (int i = 0; i < 4; i++)
            af[i] = *(const bf16x8*)&as[(wi * 64 + i * 16 + mr) * 32 + quad * 8];
        #pragma unroll
        for (int j = 0; j < 2; j++)
            bf[j] = *(const bf16x8*)&bs[(wj * 32 + j * 16 + mr) * 32 + quad * 8];
        #pragma unroll
        for (int i = 0; i < 4; i++)
        #pragma unroll
        for (int j = 0; j < 2; j++)
            acc[i][j] = __builtin_amdgcn_mfma_f32_16x16x32_bf16(af[i], bf[j], acc[i][j], 0, 0, 0);
    }
    #pragma unroll
    for (int i = 0; i < 4; i++)
    #pragma unroll
    for (int j = 0; j < 2; j++) {
        int r_ = r0 + wj * 32 + j * 16 + mr;                // col = lane&15 -> r
        int e_ = e0 + wi * 64 + i * 16 + quad * 4;          // row = quad*4+reg -> e
        float4 bv = *(const float4*)&bias[e_];
        float4 o;
        o.x = acc[i][j][0] + bv.x;
        o.y = acc[i][j][1] + bv.y;
        o.z = acc[i][j][2] + bv.z;
        o.w = acc[i][j][3] + bv.w;
        *(float4*)&out[(size_t)r_ * 1024 + e_] = o;
    }
}

// ---------------------------------------------------------------------------
// FUSED masked-softmax attention + weight rescale + AOS transpose.
// (R2-proven config, unchanged: grid 256, block 512, 8 waves, wave = head.
// HBM-bound: ~2000 cy/iter fair-share BW vs ~440 cy VALU issue; R4's
// occupancy A/B was neutral -> at its BW plateau.)
// ---------------------------------------------------------------------------
__global__ __launch_bounds__(512, 2) void k_attn(const float* __restrict__ msg,
                                                 const int* __restrict__ adj,
                                                 const unsigned short* __restrict__ Vfrag,
                                                 unsigned short* __restrict__ AOS) {
    __shared__ __align__(16) unsigned short lds_p[2][4096];  // 2 x 8 KB
    __shared__ float lds_w[8][16];                           // [h][q] rescale
    __shared__ __align__(16) unsigned short lds_t[16 * 1032]; // [q][e] pad 8

    const int t = threadIdx.x;
    const int wg = (int)blockIdx.x;
    const int swz = (wg & 7) * 32 + (wg >> 3);
    const int b = swz >> 7;
    const int q0 = (swz & 127) * 16;

    const int wv = t >> 6, lane = t & 63, mr = lane & 15, quad = lane >> 4;
    const int kl = lane >> 1;            // k_local 0..31
    const int h0 = (lane & 1) * 4;       // this thread's 4 heads
    const int lm0 = wv;                  // q-rows lm0 and lm0+8

    const float* msg_base = msg + (size_t)(b * 2048 + q0) * 2048 * 8;
    const int* adj_base = adj + (size_t)(b * 2048 + q0) * 2048;
    const unsigned short* vf_base =
        Vfrag + (((size_t)(b * 8 + wv) * 64 * 8) * 64 + lane) * 8;

    const float* mp0 = msg_base + (size_t)lm0 * 16384 + kl * 8 + h0;
    const float* mp1 = mp0 + 8 * 16384;
    const int* ap0 = adj_base + lm0 * 2048 + kl;
    const int* ap1 = ap0 + 8 * 2048;

    float4 m0r = *(const float4*)mp0;
    float4 m1r = *(const float4*)mp1;
    int a0r = ap0[0], a1r = ap1[0];
    bf16x8 vfR[8];
    #pragma unroll
    for (int nc = 0; nc < 8; nc++) vfR[nc] = *(const bf16x8*)(vf_base + nc * 512);

    float laccs[2][4] = {}, saccs[2][4] = {};
    f32x4 acc[8] = {};

    const int sr = wv * 4 + quad;
    const int afrag_off = (sr * 16 + (mr ^ (sr & 15))) * 8;

    for (int kb = 0; kb < 64; kb++) {
        unsigned short* pbuf = lds_p[kb & 1];
        float px[2][4] = {{m0r.x, m0r.y, m0r.z, m0r.w}, {m1r.x, m1r.y, m1r.z, m1r.w}};
        float bl[2];
        bl[0] = a0r ? 0.f : -1e30f;
        bl[1] = a1r ? 0.f : -1e30f;
        #pragma unroll
        for (int qi = 0; qi < 2; qi++) {
            #pragma unroll
            for (int hj = 0; hj < 4; hj++) {
                float pe = __expf(px[qi][hj] + bl[qi]);
                laccs[qi][hj] += pe;
                saccs[qi][hj] = fmaf(pe, pe, saccs[qi][hj]);
                int s = (h0 + hj) * 4 + (kl >> 3);
                int m = lm0 + qi * 8;
                pbuf[(s * 16 + (m ^ (s & 15))) * 8 + (kl & 7)] = f2bf(pe);
            }
        }
        if (kb < 63) {
            m0r = *(const float4*)(mp0 + (kb + 1) * 256);
            m1r = *(const float4*)(mp1 + (kb + 1) * 256);
            a0r = ap0[(kb + 1) * 32];
            a1r = ap1[(kb + 1) * 32];
        }
        block_sync_lgkm();
        bf16x8 afrag = *(const bf16x8*)&pbuf[afrag_off];
        #pragma unroll
        for (int nc = 0; nc < 8; nc++)
            acc[nc] = __builtin_amdgcn_mfma_f32_16x16x32_bf16(afrag, vfR[nc], acc[nc], 0, 0, 0);
        if (kb < 63) {
            const unsigned short* vp = vf_base + (size_t)(kb + 1) * 4096;
            #pragma unroll
            for (int nc = 0; nc < 8; nc++) vfR[nc] = *(const bf16x8*)(vp + nc * 512);
        }
    }

    #pragma unroll
    for (int qi = 0; qi < 2; qi++)
    #pragma unroll
    for (int hj = 0; hj < 4; hj++) {
        float l = laccs[qi][hj], s = saccs[qi][hj];
        #pragma unroll
        for (int mdist = 2; mdist <= 32; mdist <<= 1) {
            l += __shfl_xor(l, mdist, 64);
            s += __shfl_xor(s, mdist, 64);
        }
        laccs[qi][hj] = l; saccs[qi][hj] = s;
    }
    if (lane < 2) {
        #pragma unroll
        for (int qi = 0; qi < 2; qi++)
        #pragma unroll
        for (int hj = 0; hj < 4; hj++) {
            float l = laccs[qi][hj];
            lds_w[lane * 4 + hj][wv + qi * 8] = __fsqrt_rn(saccs[qi][hj]) / (l * l);
        }
    }
    block_sync_lgkm();

    float4 wq = *(const float4*)&lds_w[wv][quad * 4];
    float wqa[4] = {wq.x, wq.y, wq.z, wq.w};
    #pragma unroll
    for (int nc = 0; nc < 8; nc++) {
        int e = wv * 128 + nc * 16 + mr;
        #pragma unroll
        for (int j = 0; j < 4; j++)
            lds_t[(quad * 4 + j) * 1032 + e] = f2bf(acc[nc][j] * wqa[j]);
    }
    block_sync_lgkm();
    #pragma unroll
    for (int p = 0; p < 4; p++) {
        int le = (p * 512 + t) * 8;
        int q = le >> 10, e = le & 1023;
        uint4 v = *(const uint4*)&lds_t[q * 1032 + e];
        *(uint4*)(AOS + (size_t)(b * 2048 + q0 + q) * 1024 + e) = v;
    }
}

extern "C" void kernel_launch(void* const* d_in, const int* in_sizes, int n_in,
                              void* d_out, int out_size, void* d_ws, size_t ws_size,
                              hipStream_t stream) {
    const float* v_inv    = (const float*)d_in[0];  // [2][2048][1024]
    const float* messages = (const float*)d_in[1];  // [2][2048][2048][8]
    const int*   adjm     = (const int*)d_in[2];    // [2][2048][2048]
    const float* in_w     = (const float*)d_in[3];  // [1024][1024]
    const float* in_b     = (const float*)d_in[4];  // [1024]
    const float* out_w    = (const float*)d_in[5];  // [1024][1024]
    const float* out_b    = (const float*)d_in[6];  // [1024]
    float* out = (float*)d_out;                     // [2][2048][1024] fp32

    char* ws = (char*)d_ws;
    unsigned short* Vfrag = (unsigned short*)(ws);                      // 8 MB
    unsigned short* AOS   = (unsigned short*)(ws + (size_t)(8 << 20));  // 8 MB

    hipLaunchKernelGGL(k_gemm_in, dim3(16, 32), dim3(256), 0, stream, v_inv, in_w, in_b, Vfrag);
    hipLaunchKernelGGL(k_attn, dim3(256), dim3(512), 0, stream, messages, adjm, Vfrag, AOS);
    hipLaunchKernelGGL(k_gemm_out, dim3(64, 8), dim3(256), 0, stream, out_w, AOS, out_b, out);
}

// Round 7
// 457.359 us; speedup vs baseline: 1.0231x; 1.0231x over previous
//
#include <hip/hip_runtime.h>
#include <hip/hip_bf16.h>

typedef float f32x4 __attribute__((ext_vector_type(4)));
typedef __bf16 bf16x8 __attribute__((ext_vector_type(8)));

__device__ __forceinline__ unsigned short f2bf(float f) {
    union { float f; unsigned int u; } v; v.f = f;
    unsigned int u = v.u;
    unsigned int r = (u + 0x7fffu + ((u >> 16) & 1u)) >> 16;
    return (unsigned short)r;
}
__device__ __forceinline__ float bf2f(unsigned short u) {
    union { unsigned int u; float f; } v; v.u = ((unsigned int)u) << 16;
    return v.f;
}

// Raw workgroup barrier WITHOUT the vmcnt(0) drain __syncthreads() emits.
// 0xC07F = vmcnt(63) | expcnt(7) | lgkmcnt(0): wait only for LDS ops, leave
// global prefetch loads in flight across the barrier (m139-validated recipe).
__device__ __forceinline__ void block_sync_lgkm() {
    __asm__ __volatile__("" ::: "memory");
    __builtin_amdgcn_s_waitcnt(0xC07F);
    __builtin_amdgcn_s_barrier();
    __asm__ __volatile__("" ::: "memory");
}

// fp32 -> bf16 convert for all three inputs in ONE dispatch (range split).
__global__ __launch_bounds__(256) void k_cvt3(const float* __restrict__ a, unsigned short* __restrict__ oa,
                                              const float* __restrict__ b, unsigned short* __restrict__ ob,
                                              const float* __restrict__ c, unsigned short* __restrict__ oc) {
    int id = blockIdx.x;
    const float* src; unsigned short* dst; int i;
    if (id < 4096)      { src = a; dst = oa; i = id * 256 + threadIdx.x; }
    else if (id < 5120) { src = b; dst = ob; i = (id - 4096) * 256 + threadIdx.x; }
    else                { src = c; dst = oc; i = (id - 5120) * 256 + threadIdx.x; }
    float4 v = ((const float4*)src)[i];
    ushort4 o;
    o.x = f2bf(v.x); o.y = f2bf(v.y); o.z = f2bf(v.z); o.w = f2bf(v.w);
    ((ushort4*)dst)[i] = o;
}

// ---------------------------------------------------------------------------
// GEMM 1 (R2-proven, best-measured config: reg-staged, 128x64 tile, BK=32,
// 24 KB LDS, 2 blocks/CU). proj[r][e] = sum_d v_inv[r][d]*in_w[e][d] +
// in_b[e], written as Vfrag (bf16 MFMA B-fragment order for k_attn).
// R3/R5/R6 ablations (m97 tile, DMA 2-phase, cvt fusion) all regressed —
// this structure is the local optimum at this grid size.
// ---------------------------------------------------------------------------
__global__ __launch_bounds__(256, 4) void k_gemm_in(const unsigned short* __restrict__ A,
                                                    const unsigned short* __restrict__ B,
                                                    const float* __restrict__ bias,
                                                    unsigned short* __restrict__ Vfrag) {
    __shared__ __align__(16) unsigned short As[2][128 * 32];
    __shared__ __align__(16) unsigned short Bs[2][64 * 32];
    const int t = threadIdx.x;
    const int wv = t >> 6, lane = t & 63, mr = lane & 15, quad = lane >> 4;
    const int wi = wv >> 1, wj = wv & 1;
    const int m0 = blockIdx.y * 128, n0 = blockIdx.x * 64;

    f32x4 acc[4][2] = {};
    const int ra0 = t >> 2, ra1 = (t >> 2) + 64, rb = t >> 2;
    const int koff = (t & 3) * 8;

    uint4 pa0 = *(const uint4*)(A + (size_t)(m0 + ra0) * 1024 + koff);
    uint4 pa1 = *(const uint4*)(A + (size_t)(m0 + ra1) * 1024 + koff);
    uint4 pb  = *(const uint4*)(B + (size_t)(n0 + rb)  * 1024 + koff);

    for (int kb = 0; kb < 32; kb++) {
        unsigned short* as = As[kb & 1];
        unsigned short* bs = Bs[kb & 1];
        *(uint4*)&as[ra0 * 32 + koff] = pa0;
        *(uint4*)&as[ra1 * 32 + koff] = pa1;
        *(uint4*)&bs[rb  * 32 + koff] = pb;
        if (kb < 31) {
            int kk = (kb + 1) * 32 + koff;
            pa0 = *(const uint4*)(A + (size_t)(m0 + ra0) * 1024 + kk);
            pa1 = *(const uint4*)(A + (size_t)(m0 + ra1) * 1024 + kk);
            pb  = *(const uint4*)(B + (size_t)(n0 + rb)  * 1024 + kk);
        }
        block_sync_lgkm();
        bf16x8 af[4], bf[2];
        #pragma unroll
        for (int i = 0; i < 4; i++)
            af[i] = *(const bf16x8*)&as[(wi * 64 + i * 16 + mr) * 32 + quad * 8];
        #pragma unroll
        for (int j = 0; j < 2; j++)
            bf[j] = *(const bf16x8*)&bs[(wj * 32 + j * 16 + mr) * 32 + quad * 8];
        #pragma unroll
        for (int i = 0; i < 4; i++)
        #pragma unroll
        for (int j = 0; j < 2; j++)
            acc[i][j] = __builtin_amdgcn_mfma_f32_16x16x32_bf16(af[i], bf[j], acc[i][j], 0, 0, 0);
    }
    // epilogue: coalesced Vfrag fragment store (512 B per wave-instr)
    #pragma unroll
    for (int i = 0; i < 4; i++)
    #pragma unroll
    for (int j = 0; j < 2; j++) {
        int col = n0 + wj * 32 + j * 16 + mr;         // e
        int row0 = m0 + wi * 64 + i * 16 + quad * 4;  // r
        float be = bias[col];
        int h = col >> 7, d = col & 127;
        int bb = row0 >> 11, k = row0 & 2047;
        size_t idx8 = ((((size_t)(bb * 8 + h) * 64 + (k >> 5)) * 8 + (d >> 4)) * 64
                       + ((k >> 3) & 3) * 16 + (d & 15));
        int j0 = (quad & 1) * 4;
        ushort4 pk;
        pk.x = f2bf(acc[i][j][0] + be);
        pk.y = f2bf(acc[i][j][1] + be);
        pk.z = f2bf(acc[i][j][2] + be);
        pk.w = f2bf(acc[i][j][3] + be);
        *(ushort4*)(Vfrag + idx8 * 8 + j0) = pk;
    }
}

// ---------------------------------------------------------------------------
// GEMM 2 (R2-proven): out[r][e] = sum_d AOS[r][d]*out_w[e][d] + out_b[e].
// Operands swapped: lane holds 4 consecutive e at fixed r => float4 stores.
// ---------------------------------------------------------------------------
__global__ __launch_bounds__(256, 4) void k_gemm_out(const unsigned short* __restrict__ W,
                                                     const unsigned short* __restrict__ AOS,
                                                     const float* __restrict__ bias,
                                                     float* __restrict__ out) {
    __shared__ __align__(16) unsigned short As[2][128 * 32];
    __shared__ __align__(16) unsigned short Bs[2][64 * 32];
    const int t = threadIdx.x;
    const int wv = t >> 6, lane = t & 63, mr = lane & 15, quad = lane >> 4;
    const int wi = wv >> 1, wj = wv & 1;
    const int e0 = blockIdx.y * 128, r0 = blockIdx.x * 64;

    f32x4 acc[4][2] = {};
    const int ra0 = t >> 2, ra1 = (t >> 2) + 64, rb = t >> 2;
    const int koff = (t & 3) * 8;

    uint4 pa0 = *(const uint4*)(W   + (size_t)(e0 + ra0) * 1024 + koff);
    uint4 pa1 = *(const uint4*)(W   + (size_t)(e0 + ra1) * 1024 + koff);
    uint4 pb  = *(const uint4*)(AOS + (size_t)(r0 + rb)  * 1024 + koff);

    for (int kb = 0; kb < 32; kb++) {
        unsigned short* as = As[kb & 1];
        unsigned short* bs = Bs[kb & 1];
        *(uint4*)&as[ra0 * 32 + koff] = pa0;
        *(uint4*)&as[ra1 * 32 + koff] = pa1;
        *(uint4*)&bs[rb  * 32 + koff] = pb;
        if (kb < 31) {
            int kk = (kb + 1) * 32 + koff;
            pa0 = *(const uint4*)(W   + (size_t)(e0 + ra0) * 1024 + kk);
            pa1 = *(const uint4*)(W   + (size_t)(e0 + ra1) * 1024 + kk);
            pb  = *(const uint4*)(AOS + (size_t)(r0 + rb)  * 1024 + kk);
        }
        block_sync_lgkm();
        bf16x8 af[4], bf[2];
        #pragma unroll
        for (int i = 0; i < 4; i++)
            af[i] = *(const bf16x8*)&as[(wi * 64 + i * 16 + mr) * 32 + quad * 8];
        #pragma unroll
        for (int j = 0; j < 2; j++)
            bf[j] = *(const bf16x8*)&bs[(wj * 32 + j * 16 + mr) * 32 + quad * 8];
        #pragma unroll
        for (int i = 0; i < 4; i++)
        #pragma unroll
        for (int j = 0; j < 2; j++)
            acc[i][j] = __builtin_amdgcn_mfma_f32_16x16x32_bf16(af[i], bf[j], acc[i][j], 0, 0, 0);
    }
    #pragma unroll
    for (int i = 0; i < 4; i++)
    #pragma unroll
    for (int j = 0; j < 2; j++) {
        int r_ = r0 + wj * 32 + j * 16 + mr;                // col = lane&15 -> r
        int e_ = e0 + wi * 64 + i * 16 + quad * 4;          // row = quad*4+reg -> e
        float4 bv = *(const float4*)&bias[e_];
        float4 o;
        o.x = acc[i][j][0] + bv.x;
        o.y = acc[i][j][1] + bv.y;
        o.z = acc[i][j][2] + bv.z;
        o.w = acc[i][j][3] + bv.w;
        *(float4*)&out[(size_t)r_ * 1024 + e_] = o;
    }
}

// ---------------------------------------------------------------------------
// FUSED masked-softmax attention + weight rescale + AOS transpose.
// (R2-proven config, unchanged: grid 256, block 512, 8 waves, wave = head.
// HBM-bound at its plateau: ~317 MB traffic in ~60 us ~ 5.2 TB/s; R4's
// occupancy A/B was neutral.)
// ---------------------------------------------------------------------------
__global__ __launch_bounds__(512, 2) void k_attn(const float* __restrict__ msg,
                                                 const int* __restrict__ adj,
                                                 const unsigned short* __restrict__ Vfrag,
                                                 unsigned short* __restrict__ AOS) {
    __shared__ __align__(16) unsigned short lds_p[2][4096];  // 2 x 8 KB
    __shared__ float lds_w[8][16];                           // [h][q] rescale
    __shared__ __align__(16) unsigned short lds_t[16 * 1032]; // [q][e] pad 8

    const int t = threadIdx.x;
    const int wg = (int)blockIdx.x;
    const int swz = (wg & 7) * 32 + (wg >> 3);
    const int b = swz >> 7;
    const int q0 = (swz & 127) * 16;

    const int wv = t >> 6, lane = t & 63, mr = lane & 15, quad = lane >> 4;
    const int kl = lane >> 1;            // k_local 0..31
    const int h0 = (lane & 1) * 4;       // this thread's 4 heads
    const int lm0 = wv;                  // q-rows lm0 and lm0+8

    const float* msg_base = msg + (size_t)(b * 2048 + q0) * 2048 * 8;
    const int* adj_base = adj + (size_t)(b * 2048 + q0) * 2048;
    const unsigned short* vf_base =
        Vfrag + (((size_t)(b * 8 + wv) * 64 * 8) * 64 + lane) * 8;

    const float* mp0 = msg_base + (size_t)lm0 * 16384 + kl * 8 + h0;
    const float* mp1 = mp0 + 8 * 16384;
    const int* ap0 = adj_base + lm0 * 2048 + kl;
    const int* ap1 = ap0 + 8 * 2048;

    float4 m0r = *(const float4*)mp0;
    float4 m1r = *(const float4*)mp1;
    int a0r = ap0[0], a1r = ap1[0];
    bf16x8 vfR[8];
    #pragma unroll
    for (int nc = 0; nc < 8; nc++) vfR[nc] = *(const bf16x8*)(vf_base + nc * 512);

    float laccs[2][4] = {}, saccs[2][4] = {};
    f32x4 acc[8] = {};

    const int sr = wv * 4 + quad;
    const int afrag_off = (sr * 16 + (mr ^ (sr & 15))) * 8;

    for (int kb = 0; kb < 64; kb++) {
        unsigned short* pbuf = lds_p[kb & 1];
        float px[2][4] = {{m0r.x, m0r.y, m0r.z, m0r.w}, {m1r.x, m1r.y, m1r.z, m1r.w}};
        float bl[2];
        bl[0] = a0r ? 0.f : -1e30f;
        bl[1] = a1r ? 0.f : -1e30f;
        #pragma unroll
        for (int qi = 0; qi < 2; qi++) {
            #pragma unroll
            for (int hj = 0; hj < 4; hj++) {
                float pe = __expf(px[qi][hj] + bl[qi]);
                laccs[qi][hj] += pe;
                saccs[qi][hj] = fmaf(pe, pe, saccs[qi][hj]);
                int s = (h0 + hj) * 4 + (kl >> 3);
                int m = lm0 + qi * 8;
                pbuf[(s * 16 + (m ^ (s & 15))) * 8 + (kl & 7)] = f2bf(pe);
            }
        }
        if (kb < 63) {
            m0r = *(const float4*)(mp0 + (kb + 1) * 256);
            m1r = *(const float4*)(mp1 + (kb + 1) * 256);
            a0r = ap0[(kb + 1) * 32];
            a1r = ap1[(kb + 1) * 32];
        }
        block_sync_lgkm();
        bf16x8 afrag = *(const bf16x8*)&pbuf[afrag_off];
        #pragma unroll
        for (int nc = 0; nc < 8; nc++)
            acc[nc] = __builtin_amdgcn_mfma_f32_16x16x32_bf16(afrag, vfR[nc], acc[nc], 0, 0, 0);
        if (kb < 63) {
            const unsigned short* vp = vf_base + (size_t)(kb + 1) * 4096;
            #pragma unroll
            for (int nc = 0; nc < 8; nc++) vfR[nc] = *(const bf16x8*)(vp + nc * 512);
        }
    }

    #pragma unroll
    for (int qi = 0; qi < 2; qi++)
    #pragma unroll
    for (int hj = 0; hj < 4; hj++) {
        float l = laccs[qi][hj], s = saccs[qi][hj];
        #pragma unroll
        for (int mdist = 2; mdist <= 32; mdist <<= 1) {
            l += __shfl_xor(l, mdist, 64);
            s += __shfl_xor(s, mdist, 64);
        }
        laccs[qi][hj] = l; saccs[qi][hj] = s;
    }
    if (lane < 2) {
        #pragma unroll
        for (int qi = 0; qi < 2; qi++)
        #pragma unroll
        for (int hj = 0; hj < 4; hj++) {
            float l = laccs[qi][hj];
            lds_w[lane * 4 + hj][wv + qi * 8] = __fsqrt_rn(saccs[qi][hj]) / (l * l);
        }
    }
    block_sync_lgkm();

    float4 wq = *(const float4*)&lds_w[wv][quad * 4];
    float wqa[4] = {wq.x, wq.y, wq.z, wq.w};
    #pragma unroll
    for (int nc = 0; nc < 8; nc++) {
        int e = wv * 128 + nc * 16 + mr;
        #pragma unroll
        for (int j = 0; j < 4; j++)
            lds_t[(quad * 4 + j) * 1032 + e] = f2bf(acc[nc][j] * wqa[j]);
    }
    block_sync_lgkm();
    #pragma unroll
    for (int p = 0; p < 4; p++) {
        int le = (p * 512 + t) * 8;
        int q = le >> 10, e = le & 1023;
        uint4 v = *(const uint4*)&lds_t[q * 1032 + e];
        *(uint4*)(AOS + (size_t)(b * 2048 + q0 + q) * 1024 + e) = v;
    }
}

extern "C" void kernel_launch(void* const* d_in, const int* in_sizes, int n_in,
                              void* d_out, int out_size, void* d_ws, size_t ws_size,
                              hipStream_t stream) {
    const float* v_inv    = (const float*)d_in[0];  // [2][2048][1024]
    const float* messages = (const float*)d_in[1];  // [2][2048][2048][8]
    const int*   adjm     = (const int*)d_in[2];    // [2][2048][2048]
    const float* in_w     = (const float*)d_in[3];  // [1024][1024]
    const float* in_b     = (const float*)d_in[4];  // [1024]
    const float* out_w    = (const float*)d_in[5];  // [1024][1024]
    const float* out_b    = (const float*)d_in[6];  // [1024]
    float* out = (float*)d_out;                     // [2][2048][1024] fp32

    char* ws = (char*)d_ws;
    unsigned short* vinv_bf = (unsigned short*)(ws);                        // 8 MB
    unsigned short* inw_bf  = (unsigned short*)(ws + (size_t)(8  << 20));   // 2 MB
    unsigned short* outw_bf = (unsigned short*)(ws + (size_t)(10 << 20));   // 2 MB
    unsigned short* Vfrag   = (unsigned short*)(ws + (size_t)(12 << 20));   // 8 MB
    unsigned short* AOS     = (unsigned short*)(ws + (size_t)(20 << 20));   // 8 MB

    hipLaunchKernelGGL(k_cvt3, dim3(6144), dim3(256), 0, stream,
                       v_inv, vinv_bf, in_w, inw_bf, out_w, outw_bf);
    hipLaunchKernelGGL(k_gemm_in, dim3(16, 32), dim3(256), 0, stream, vinv_bf, inw_bf, in_b, Vfrag);
    hipLaunchKernelGGL(k_attn, dim3(256), dim3(512), 0, stream, messages, adjm, Vfrag, AOS);
    hipLaunchKernelGGL(k_gemm_out, dim3(64, 8), dim3(256), 0, stream, outw_bf, AOS, out_b, out);
}